// Round 3
// baseline (1288.515 us; speedup 1.0000x reference)
//
#include <hip/hip_runtime.h>
#include <hip/hip_bf16.h>
#include <cstdint>

typedef __bf16 bf16;
typedef __attribute__((ext_vector_type(8))) __bf16 bf16x8;
typedef __attribute__((ext_vector_type(4))) __bf16 bf16x4;
typedef __attribute__((ext_vector_type(4))) float f32x4;
typedef __attribute__((ext_vector_type(4))) unsigned int u32x4;

#define B_ 4
#define S_ 8192
#define D_ 1024
#define H_ 16
#define HD_ 64
#define W_ 512
#define M_ (B_*S_)   // 32768 rows total

#define EXP2F(x) __builtin_amdgcn_exp2f(x)

__device__ __forceinline__ void async16(const void* g, void* l) {
  __builtin_amdgcn_global_load_lds(
      (const __attribute__((address_space(1))) unsigned int*)g,
      (__attribute__((address_space(3))) unsigned int*)l, 16, 0, 0);
}

// ---------------- cast f32 -> bf16 ----------------
__global__ void cast_f32_bf16(const float* __restrict__ in, bf16* __restrict__ out, int n4) {
  int i = blockIdx.x * blockDim.x + threadIdx.x;
  int stride = gridDim.x * blockDim.x;
  for (; i < n4; i += stride) {
    f32x4 v = ((const f32x4*)in)[i];
    bf16x4 o = { (bf16)v[0], (bf16)v[1], (bf16)v[2], (bf16)v[3] };
    ((bf16x4*)out)[i] = o;
  }
}

// ---------------- GEMM: C = A(MxK) * Bw(NxK)^T + bias ----------------
// MODE 0: bf16 out row-major   MODE 1: bf16 out V-transposed per batch   MODE 2: f32 out
template<int MODE>
__global__ void __launch_bounds__(256, 2) gemm_bt(
    const bf16* __restrict__ A, const bf16* __restrict__ Bw,
    const float* __restrict__ bias, void* __restrict__ outp, float scale)
{
  constexpr int K = D_, N = D_;
  __shared__ bf16 As[128*32];
  __shared__ bf16 Bs[128*32];
  int bid = blockIdx.x;                       // 2048 blocks, 2048 % 8 == 0
  int nid = (bid & 7) * 256 + (bid >> 3);     // bijective XCD swizzle
  int bm = nid >> 3, bn = nid & 7;
  const int tid = threadIdx.x, lane = tid & 63;
  const int w = tid >> 6, wr = w >> 1, wc = w & 1;
  f32x4 acc[4][4] = {};
  const int r0 = tid >> 2;               // row (0..63) per 16B segment
  const int kbyte = (tid & 3) * 16;      // byte within 64B row
  const char* Ab = (const char*)(A + (size_t)bm * 128 * K);
  const char* Bb = (const char*)(Bw + (size_t)bn * 128 * K);
  for (int kt = 0; kt < K; kt += 32) {
    __syncthreads();
    const size_t cb = (size_t)kt * 2 + kbyte;
    async16(Ab + (size_t)r0      * (K*2) + cb, (char*)As + tid*16);
    async16(Ab + (size_t)(r0+64) * (K*2) + cb, (char*)As + 4096 + tid*16);
    async16(Bb + (size_t)r0      * (K*2) + cb, (char*)Bs + tid*16);
    async16(Bb + (size_t)(r0+64) * (K*2) + cb, (char*)Bs + 4096 + tid*16);
    __syncthreads();
    bf16x8 a[4], b[4];
#pragma unroll
    for (int mi = 0; mi < 4; ++mi)
      a[mi] = *(const bf16x8*)(As + (wr*64 + mi*16 + (lane & 15))*32 + ((lane >> 4)*8));
#pragma unroll
    for (int ni = 0; ni < 4; ++ni)
      b[ni] = *(const bf16x8*)(Bs + (wc*64 + ni*16 + (lane & 15))*32 + ((lane >> 4)*8));
#pragma unroll
    for (int mi = 0; mi < 4; ++mi)
#pragma unroll
      for (int ni = 0; ni < 4; ++ni)
        acc[mi][ni] = __builtin_amdgcn_mfma_f32_16x16x32_bf16(a[mi], b[ni], acc[mi][ni], 0, 0, 0);
  }
  int row0 = bm*128 + wr*64, col0 = bn*128 + wc*64;
  int rsub = (lane >> 4) * 4;
#pragma unroll
  for (int ni = 0; ni < 4; ++ni) {
    int col = col0 + ni*16 + (lane & 15);
    float bz = bias[col];
#pragma unroll
    for (int mi = 0; mi < 4; ++mi) {
#pragma unroll
      for (int r = 0; r < 4; ++r) {
        int row = row0 + mi*16 + rsub + r;
        float v = (acc[mi][ni][r] + bz) * scale;
        if (MODE == 0) {
          ((bf16*)outp)[(size_t)row * N + col] = (bf16)v;
        } else if (MODE == 1) {
          // vt[b][col][s]  (col = h*64+hd), b = row/S, s = row%S
          ((bf16*)outp)[((size_t)(row >> 13) * D_ + col) * S_ + (row & (S_-1))] = (bf16)v;
        } else {
          ((float*)outp)[(size_t)row * N + col] = v;
        }
      }
    }
  }
}

// ---------------- attention (swapped QK^T, no K/V LDS, lane-local softmax) ----
// grid: 8192 blocks, 256 threads = 4 waves x 16 q-rows.
// XCD grouping: 8 q-tile blocks of one (b,n,h) land consecutively on one XCD.
__global__ void __launch_bounds__(256, 4) attn_kernel(
    const bf16* __restrict__ Q, const bf16* __restrict__ Kb,
    const bf16* __restrict__ Vt, bf16* __restrict__ Ao)
{
  __shared__ char Plds[4][2][2048];   // per-wave, parity double-buffered P
  int x = blockIdx.x;
  int xcd = x & 7, t = (x >> 3) & 7, gg = x >> 6;
  int g = xcd + 8 * gg;               // group id 0..1023, group -> one XCD
  int h = g & 15, n = (g >> 4) & 15, b = g >> 8;
  int qt = t;
  int tid = threadIdx.x, lane = tid & 63, w = tid >> 6;
  int g4 = lane >> 4;                 // lane group 0..3
  int qi = lane & 15;                 // this lane's q (within 16-row tile)
  int qrow = n * W_ + qt * 64 + w * 16;

  const size_t qoff = ((size_t)(b * S_ + qrow + qi)) * D_ + h * 64 + g4 * 8;
  bf16x8 qf0 = *(const bf16x8*)(Q + qoff);        // Q pre-scaled by log2e/8
  bf16x8 qf1 = *(const bf16x8*)(Q + qoff + 32);

  const bf16* Kg = Kb + ((size_t)b * S_) * D_ + h * 64;
  const bf16* Vg = Vt + ((size_t)(b * H_ + h) * HD_) * S_;

  f32x4 o[4] = {};
  float m_r = -3.0e38f, l_r = 0.f;
  const int pswz = (qi & 7) << 4;

  const int c0 = (n == 0) ? 8 : 0;
  const int ksbase = (n - 1) * W_;
  for (int c = c0; c < 16; ++c) {
    int ks = ksbase + c * 64;
    char* pb = &Plds[w][c & 1][0];
    // ---- swapped QK^T: st[ni] holds S^T tile (rows=k, cols=q)
    f32x4 st[4];
#pragma unroll
    for (int ni = 0; ni < 4; ++ni) {
      const bf16* kr = Kg + (size_t)(ks + ni * 16 + qi) * D_ + g4 * 8;
      bf16x8 kf0 = *(const bf16x8*)(kr);
      bf16x8 kf1 = *(const bf16x8*)(kr + 32);
      f32x4 z = {};
      z = __builtin_amdgcn_mfma_f32_16x16x32_bf16(kf0, qf0, z, 0, 0, 0);
      z = __builtin_amdgcn_mfma_f32_16x16x32_bf16(kf1, qf1, z, 0, 0, 0);
      st[ni] = z;
    }
    // ---- lane-local online softmax (log2 domain)
    float mx = st[0][0];
#pragma unroll
    for (int ni = 0; ni < 4; ++ni)
#pragma unroll
      for (int r = 0; r < 4; ++r) mx = fmaxf(mx, st[ni][r]);
    mx = fmaxf(mx, __shfl_xor(mx, 16));
    mx = fmaxf(mx, __shfl_xor(mx, 32));
    if (!__all(mx - m_r <= 8.0f)) {    // defer-max: rescale only on real growth
      float mn = fmaxf(m_r, mx);
      float sc = EXP2F(m_r - mn);
      m_r = mn;
      l_r *= sc;
#pragma unroll
      for (int ai = 0; ai < 4; ++ai)
#pragma unroll
        for (int r = 0; r < 4; ++r) o[ai][r] *= sc;
    }
    float ls = 0.f;
    bf16x4 pw[4];
#pragma unroll
    for (int ni = 0; ni < 4; ++ni)
#pragma unroll
      for (int r = 0; r < 4; ++r) {
        float p = EXP2F(st[ni][r] - m_r);
        ls += p;
        pw[ni][r] = (bf16)p;
      }
    l_r += ls;
    // ---- P roundtrip through per-wave LDS (b64 writes, b128 reads)
#pragma unroll
    for (int ni = 0; ni < 4; ++ni)
      *(bf16x4*)(pb + qi * 128 + ((ni * 32 + g4 * 8) ^ pswz)) = pw[ni];
    asm volatile("s_waitcnt lgkmcnt(0)" ::: "memory");
    __builtin_amdgcn_sched_barrier(0);
    bf16x8 pa0 = *(const bf16x8*)(pb + qi * 128 + ((g4 * 16) ^ pswz));
    bf16x8 pa1 = *(const bf16x8*)(pb + qi * 128 + ((64 + g4 * 16) ^ pswz));
    __builtin_amdgcn_sched_barrier(0x7F);   // everything but DS may cross
    // ---- PV: O^T[hd][q] += V^T * P^T
#pragma unroll
    for (int ai = 0; ai < 4; ++ai) {
      const bf16* vr = Vg + (size_t)(ai * 16 + qi) * S_ + ks + g4 * 8;
      bf16x8 vf0 = *(const bf16x8*)(vr);
      bf16x8 vf1 = *(const bf16x8*)(vr + 32);
      o[ai] = __builtin_amdgcn_mfma_f32_16x16x32_bf16(vf0, pa0, o[ai], 0, 0, 0);
      o[ai] = __builtin_amdgcn_mfma_f32_16x16x32_bf16(vf1, pa1, o[ai], 0, 0, 0);
    }
  }
  // ---- final l reduce across the 4 lane groups, normalize, store
  float lt = l_r + __shfl_xor(l_r, 16);
  lt += __shfl_xor(lt, 32);
  float inv = 1.0f / lt;
  size_t orow = ((size_t)(b * S_ + qrow + qi)) * D_ + h * 64 + g4 * 4;
#pragma unroll
  for (int ai = 0; ai < 4; ++ai) {
    bf16x4 ov;
#pragma unroll
    for (int r = 0; r < 4; ++r) ov[r] = (bf16)(o[ai][r] * inv);
    *(bf16x4*)(Ao + orow + ai * 16) = ov;
  }
}

extern "C" void kernel_launch(void* const* d_in, const int* in_sizes, int n_in,
                              void* d_out, int out_size, void* d_ws, size_t ws_size,
                              hipStream_t stream) {
  const float* x  = (const float*)d_in[0];
  const float* wq = (const float*)d_in[1];
  const float* bq = (const float*)d_in[2];
  const float* wk = (const float*)d_in[3];
  const float* bk = (const float*)d_in[4];
  const float* wv = (const float*)d_in[5];
  const float* bv = (const float*)d_in[6];
  const float* wo = (const float*)d_in[7];
  const float* bo = (const float*)d_in[8];
  float* out = (float*)d_out;

  char* ws = (char*)d_ws;
  const size_t sz = (size_t)M_ * D_ * 2;   // 64 MiB per bf16 activation buffer
  bf16* xb  = (bf16*)(ws + 0*sz);
  bf16* qb  = (bf16*)(ws + 1*sz);
  bf16* kb  = (bf16*)(ws + 2*sz);
  bf16* vt  = (bf16*)(ws + 3*sz);
  bf16* ao  = (bf16*)(ws + 4*sz);
  bf16* wqb = (bf16*)(ws + 5*sz);
  bf16* wkb = wqb + (size_t)D_*D_;
  bf16* wvb = wkb + (size_t)D_*D_;
  bf16* wob = wvb + (size_t)D_*D_;

  cast_f32_bf16<<<2048, 256, 0, stream>>>(x,  xb,  M_*D_/4);
  cast_f32_bf16<<<512,  256, 0, stream>>>(wq, wqb, D_*D_/4);
  cast_f32_bf16<<<512,  256, 0, stream>>>(wk, wkb, D_*D_/4);
  cast_f32_bf16<<<512,  256, 0, stream>>>(wv, wvb, D_*D_/4);
  cast_f32_bf16<<<512,  256, 0, stream>>>(wo, wob, D_*D_/4);

  // Q pre-scaled by (1/sqrt(64)) * log2(e) so attention exp runs in exp2 domain
  gemm_bt<0><<<2048, 256, 0, stream>>>(xb, wqb, bq, qb, 0.125f * 1.44269504f);
  gemm_bt<0><<<2048, 256, 0, stream>>>(xb, wkb, bk, kb, 1.0f);
  gemm_bt<1><<<2048, 256, 0, stream>>>(xb, wvb, bv, vt, 1.0f);    // V stored transposed

  attn_kernel<<<8192, 256, 0, stream>>>(qb, kb, vt, ao);

  gemm_bt<2><<<2048, 256, 0, stream>>>(ao, wob, bo, out, 1.0f);
}

// Round 4
// 614.513 us; speedup vs baseline: 2.0968x; 2.0968x over previous
//
#include <hip/hip_runtime.h>
#include <hip/hip_bf16.h>
#include <cstdint>

typedef __bf16 bf16;
typedef __attribute__((ext_vector_type(8))) __bf16 bf16x8;
typedef __attribute__((ext_vector_type(4))) __bf16 bf16x4;
typedef __attribute__((ext_vector_type(4))) float f32x4;
typedef __attribute__((ext_vector_type(4))) unsigned int u32x4;

#define B_ 4
#define S_ 8192
#define D_ 1024
#define H_ 16
#define HD_ 64
#define W_ 512
#define M_ (B_*S_)   // 32768 rows total

#define EXP2F(x) __builtin_amdgcn_exp2f(x)
#define MFMA16(a,b,c) __builtin_amdgcn_mfma_f32_16x16x32_bf16(a,b,c,0,0,0)

__device__ __forceinline__ void async16(const void* g, void* l) {
  __builtin_amdgcn_global_load_lds(
      (const __attribute__((address_space(1))) unsigned int*)g,
      (__attribute__((address_space(3))) unsigned int*)l, 16, 0, 0);
}

// ---------------- cast f32 -> bf16 ----------------
__global__ void cast_f32_bf16(const float* __restrict__ in, bf16* __restrict__ out, int n4) {
  int i = blockIdx.x * blockDim.x + threadIdx.x;
  int stride = gridDim.x * blockDim.x;
  for (; i < n4; i += stride) {
    f32x4 v = ((const f32x4*)in)[i];
    bf16x4 o = { (bf16)v[0], (bf16)v[1], (bf16)v[2], (bf16)v[3] };
    ((bf16x4*)out)[i] = o;
  }
}

// ---------------- GEMM: C = A(MxK) * Bw(NxK)^T + bias ----------------
// MODE 0: bf16 out row-major   MODE 1: bf16 out V-transposed per batch   MODE 2: f32 out
template<int MODE>
__global__ void __launch_bounds__(256, 2) gemm_bt(
    const bf16* __restrict__ A, const bf16* __restrict__ Bw,
    const float* __restrict__ bias, void* __restrict__ outp, float scale)
{
  constexpr int K = D_, N = D_;
  __shared__ bf16 As[128*32];
  __shared__ bf16 Bs[128*32];
  int bid = blockIdx.x;                       // 2048 blocks, 2048 % 8 == 0
  int nid = (bid & 7) * 256 + (bid >> 3);     // bijective XCD swizzle
  int bm = nid >> 3, bn = nid & 7;
  const int tid = threadIdx.x, lane = tid & 63;
  const int w = tid >> 6, wr = w >> 1, wc = w & 1;
  f32x4 acc[4][4] = {};
  const int r0 = tid >> 2;               // row (0..63) per 16B segment
  const int kbyte = (tid & 3) * 16;      // byte within 64B row
  const char* Ab = (const char*)(A + (size_t)bm * 128 * K);
  const char* Bb = (const char*)(Bw + (size_t)bn * 128 * K);
  for (int kt = 0; kt < K; kt += 32) {
    __syncthreads();
    const size_t cb = (size_t)kt * 2 + kbyte;
    async16(Ab + (size_t)r0      * (K*2) + cb, (char*)As + tid*16);
    async16(Ab + (size_t)(r0+64) * (K*2) + cb, (char*)As + 4096 + tid*16);
    async16(Bb + (size_t)r0      * (K*2) + cb, (char*)Bs + tid*16);
    async16(Bb + (size_t)(r0+64) * (K*2) + cb, (char*)Bs + 4096 + tid*16);
    __syncthreads();
    bf16x8 a[4], b[4];
#pragma unroll
    for (int mi = 0; mi < 4; ++mi)
      a[mi] = *(const bf16x8*)(As + (wr*64 + mi*16 + (lane & 15))*32 + ((lane >> 4)*8));
#pragma unroll
    for (int ni = 0; ni < 4; ++ni)
      b[ni] = *(const bf16x8*)(Bs + (wc*64 + ni*16 + (lane & 15))*32 + ((lane >> 4)*8));
#pragma unroll
    for (int mi = 0; mi < 4; ++mi)
#pragma unroll
      for (int ni = 0; ni < 4; ++ni)
        acc[mi][ni] = MFMA16(a[mi], b[ni], acc[mi][ni]);
  }
  int row0 = bm*128 + wr*64, col0 = bn*128 + wc*64;
  int rsub = (lane >> 4) * 4;
#pragma unroll
  for (int ni = 0; ni < 4; ++ni) {
    int col = col0 + ni*16 + (lane & 15);
    float bz = bias[col];
#pragma unroll
    for (int mi = 0; mi < 4; ++mi) {
#pragma unroll
      for (int r = 0; r < 4; ++r) {
        int row = row0 + mi*16 + rsub + r;
        float v = (acc[mi][ni][r] + bz) * scale;
        if (MODE == 0) {
          ((bf16*)outp)[(size_t)row * N + col] = (bf16)v;
        } else if (MODE == 1) {
          // vt[b][col][s]  (col = h*64+hd), b = row/S, s = row%S
          ((bf16*)outp)[((size_t)(row >> 13) * D_ + col) * S_ + (row & (S_-1))] = (bf16)v;
        } else {
          ((float*)outp)[(size_t)row * N + col] = v;
        }
      }
    }
  }
}

// ---------------- attention ----------------
// Staged K/V in double-buffered swizzled LDS + async-split prefetch;
// swapped QK^T with lane-local exp2 softmax + defer-max; P via per-wave LDS.
// grid: 8192 blocks (XCD-grouped), 256 threads = 4 waves x 16 q-rows.
__global__ void __launch_bounds__(256, 3) attn_kernel(
    const bf16* __restrict__ Q, const bf16* __restrict__ Kb,
    const bf16* __restrict__ Vt, bf16* __restrict__ Ao)
{
  __shared__ char Klds[2][8192];   // [buf][64 keys x 128B (d-major, swizzled)]
  __shared__ char Vlds[2][8192];   // [buf][64 hd   x 128B (s-major, swizzled)]
  __shared__ char Plds[4][2048];   // per-wave P [16 q x 128B]
  int x = blockIdx.x;
  int xcd = x & 7, qt = (x >> 3) & 7, gg = x >> 6;
  int g = xcd + 8 * gg;            // 8 q-tile blocks of one (b,n,h) -> one XCD
  int h = g & 15, n = (g >> 4) & 15, b = g >> 8;
  int tid = threadIdx.x, lane = tid & 63, w = tid >> 6;
  int g4 = lane >> 4, qi = lane & 15;
  int qrow = n * W_ + qt * 64 + w * 16;

  const size_t qoff = ((size_t)(b * S_ + qrow + qi)) * D_ + h * 64 + g4 * 8;
  bf16x8 qf0 = *(const bf16x8*)(Q + qoff);      // Q pre-scaled by log2e/8
  bf16x8 qf1 = *(const bf16x8*)(Q + qoff + 32);

  const bf16* Kg = Kb + ((size_t)b * S_) * D_ + h * 64;
  const bf16* Vg = Vt + ((size_t)(b * H_ + h) * HD_) * S_;

  const int srow = tid >> 3, scol = tid & 7;     // staging: 32 rows x 8 segs
  const int sswz = (srow & 7) << 4;

  f32x4 o[4] = {};
  float m_r = -3.0e38f, l_r = 0.f;
  const int fsw = (qi & 7) << 4;   // fragment/P swizzle (row&7 == qi&7)
  char* pb = &Plds[w][0];

  const int c0 = (n == 0) ? 8 : 0;
  const int ksbase = (n - 1) * W_;

  u32x4 pk0, pk1, pv0, pv1;
  {  // prologue: stage chunk c0 into buffer 0
    int ks = ksbase + c0 * 64;
    pk0 = *(const u32x4*)(Kg + (size_t)(ks + srow)      * D_ + scol * 8);
    pk1 = *(const u32x4*)(Kg + (size_t)(ks + srow + 32) * D_ + scol * 8);
    pv0 = *(const u32x4*)(Vg + (size_t)srow        * S_ + ks + scol * 8);
    pv1 = *(const u32x4*)(Vg + (size_t)(srow + 32) * S_ + ks + scol * 8);
    *(u32x4*)(Klds[0] + srow        * 128 + ((scol * 16) ^ sswz)) = pk0;
    *(u32x4*)(Klds[0] + (srow + 32) * 128 + ((scol * 16) ^ sswz)) = pk1;
    *(u32x4*)(Vlds[0] + srow        * 128 + ((scol * 16) ^ sswz)) = pv0;
    *(u32x4*)(Vlds[0] + (srow + 32) * 128 + ((scol * 16) ^ sswz)) = pv1;
  }
  __syncthreads();
  int cur = 0;
  for (int c = c0; c < 16; ++c) {
    bool pre = (c < 15);
    if (pre) {  // T14: issue next chunk's global loads early; write after compute
      int ks2 = ksbase + (c + 1) * 64;
      pk0 = *(const u32x4*)(Kg + (size_t)(ks2 + srow)      * D_ + scol * 8);
      pk1 = *(const u32x4*)(Kg + (size_t)(ks2 + srow + 32) * D_ + scol * 8);
      pv0 = *(const u32x4*)(Vg + (size_t)srow        * S_ + ks2 + scol * 8);
      pv1 = *(const u32x4*)(Vg + (size_t)(srow + 32) * S_ + ks2 + scol * 8);
    }
    const char* kbuf = Klds[cur];
    const char* vbuf = Vlds[cur];
    // ---- swapped QK^T: st[ni] rows=k, cols=q
    f32x4 st[4];
    __builtin_amdgcn_s_setprio(1);
#pragma unroll
    for (int ni = 0; ni < 4; ++ni) {
      const char* kbase = kbuf + (ni * 16 + qi) * 128;
      bf16x8 kf0 = *(const bf16x8*)(kbase + ((g4 * 16) ^ fsw));
      bf16x8 kf1 = *(const bf16x8*)(kbase + ((64 + g4 * 16) ^ fsw));
      f32x4 z = {};
      z = MFMA16(kf0, qf0, z);
      z = MFMA16(kf1, qf1, z);
      st[ni] = z;
    }
    __builtin_amdgcn_s_setprio(0);
    // ---- lane-local online softmax (exp2 domain)
    float mx = st[0][0];
#pragma unroll
    for (int ni = 0; ni < 4; ++ni)
#pragma unroll
      for (int r = 0; r < 4; ++r) mx = fmaxf(mx, st[ni][r]);
    mx = fmaxf(mx, __shfl_xor(mx, 16));
    mx = fmaxf(mx, __shfl_xor(mx, 32));
    if (!__all(mx - m_r <= 8.0f)) {   // defer-max
      float mn = fmaxf(m_r, mx);
      float sc = EXP2F(m_r - mn);
      m_r = mn;
      l_r *= sc;
#pragma unroll
      for (int ai = 0; ai < 4; ++ai)
#pragma unroll
        for (int r = 0; r < 4; ++r) o[ai][r] *= sc;
    }
    float ls = 0.f;
    bf16x4 pw[4];
#pragma unroll
    for (int ni = 0; ni < 4; ++ni)
#pragma unroll
      for (int r = 0; r < 4; ++r) {
        float p = EXP2F(st[ni][r] - m_r);
        ls += p;
        pw[ni][r] = (bf16)p;
      }
    l_r += ls;
    // ---- P roundtrip through per-wave LDS
#pragma unroll
    for (int ni = 0; ni < 4; ++ni)
      *(bf16x4*)(pb + qi * 128 + ((ni * 32 + g4 * 8) ^ fsw)) = pw[ni];
    asm volatile("s_waitcnt lgkmcnt(0)" ::: "memory");
    __builtin_amdgcn_sched_barrier(0);
    bf16x8 pa0 = *(const bf16x8*)(pb + qi * 128 + ((g4 * 16) ^ fsw));
    bf16x8 pa1 = *(const bf16x8*)(pb + qi * 128 + ((64 + g4 * 16) ^ fsw));
    __builtin_amdgcn_sched_barrier(0x7F);
    // ---- PV: O^T[hd][q] += V^T * P^T
    __builtin_amdgcn_s_setprio(1);
#pragma unroll
    for (int ai = 0; ai < 4; ++ai) {
      const char* vbase = vbuf + (ai * 16 + qi) * 128;
      bf16x8 vf0 = *(const bf16x8*)(vbase + ((g4 * 16) ^ fsw));
      bf16x8 vf1 = *(const bf16x8*)(vbase + ((64 + g4 * 16) ^ fsw));
      o[ai] = MFMA16(vf0, pa0, o[ai]);
      o[ai] = MFMA16(vf1, pa1, o[ai]);
    }
    __builtin_amdgcn_s_setprio(0);
    // ---- write prefetched chunk into the other buffer, single barrier
    if (pre) {
      int nb = cur ^ 1;
      *(u32x4*)(Klds[nb] + srow        * 128 + ((scol * 16) ^ sswz)) = pk0;
      *(u32x4*)(Klds[nb] + (srow + 32) * 128 + ((scol * 16) ^ sswz)) = pk1;
      *(u32x4*)(Vlds[nb] + srow        * 128 + ((scol * 16) ^ sswz)) = pv0;
      *(u32x4*)(Vlds[nb] + (srow + 32) * 128 + ((scol * 16) ^ sswz)) = pv1;
    }
    __syncthreads();
    cur ^= 1;
  }
  // ---- final l reduce across the 4 lane groups, normalize, store
  float lt = l_r + __shfl_xor(l_r, 16);
  lt += __shfl_xor(lt, 32);
  float inv = 1.0f / lt;
  size_t orow = ((size_t)(b * S_ + qrow + qi)) * D_ + h * 64 + g4 * 4;
#pragma unroll
  for (int ai = 0; ai < 4; ++ai) {
    bf16x4 ov;
#pragma unroll
    for (int r = 0; r < 4; ++r) ov[r] = (bf16)(o[ai][r] * inv);
    *(bf16x4*)(Ao + orow + ai * 16) = ov;
  }
}

extern "C" void kernel_launch(void* const* d_in, const int* in_sizes, int n_in,
                              void* d_out, int out_size, void* d_ws, size_t ws_size,
                              hipStream_t stream) {
  const float* x  = (const float*)d_in[0];
  const float* wq = (const float*)d_in[1];
  const float* bq = (const float*)d_in[2];
  const float* wk = (const float*)d_in[3];
  const float* bk = (const float*)d_in[4];
  const float* wv = (const float*)d_in[5];
  const float* bv = (const float*)d_in[6];
  const float* wo = (const float*)d_in[7];
  const float* bo = (const float*)d_in[8];
  float* out = (float*)d_out;

  char* ws = (char*)d_ws;
  const size_t sz = (size_t)M_ * D_ * 2;   // 64 MiB per bf16 activation buffer
  bf16* xb  = (bf16*)(ws + 0*sz);
  bf16* qb  = (bf16*)(ws + 1*sz);
  bf16* kb  = (bf16*)(ws + 2*sz);
  bf16* vt  = (bf16*)(ws + 3*sz);
  bf16* ao  = (bf16*)(ws + 4*sz);
  bf16* wqb = (bf16*)(ws + 5*sz);
  bf16* wkb = wqb + (size_t)D_*D_;
  bf16* wvb = wkb + (size_t)D_*D_;
  bf16* wob = wvb + (size_t)D_*D_;

  cast_f32_bf16<<<2048, 256, 0, stream>>>(x,  xb,  M_*D_/4);
  cast_f32_bf16<<<512,  256, 0, stream>>>(wq, wqb, D_*D_/4);
  cast_f32_bf16<<<512,  256, 0, stream>>>(wk, wkb, D_*D_/4);
  cast_f32_bf16<<<512,  256, 0, stream>>>(wv, wvb, D_*D_/4);
  cast_f32_bf16<<<512,  256, 0, stream>>>(wo, wob, D_*D_/4);

  // Q pre-scaled by (1/sqrt(64)) * log2(e) so attention exp runs in exp2 domain
  gemm_bt<0><<<2048, 256, 0, stream>>>(xb, wqb, bq, qb, 0.125f * 1.44269504f);
  gemm_bt<0><<<2048, 256, 0, stream>>>(xb, wkb, bk, kb, 1.0f);
  gemm_bt<1><<<2048, 256, 0, stream>>>(xb, wvb, bv, vt, 1.0f);    // V stored transposed

  attn_kernel<<<8192, 256, 0, stream>>>(qb, kb, vt, ao);

  gemm_bt<2><<<2048, 256, 0, stream>>>(ao, wob, bo, out, 1.0f);
}

// Round 5
// 575.479 us; speedup vs baseline: 2.2390x; 1.0678x over previous
//
#include <hip/hip_runtime.h>
#include <hip/hip_bf16.h>
#include <cstdint>

typedef __bf16 bf16;
typedef __attribute__((ext_vector_type(8))) __bf16 bf16x8;
typedef __attribute__((ext_vector_type(4))) __bf16 bf16x4;
typedef __attribute__((ext_vector_type(4))) float f32x4;
typedef __attribute__((ext_vector_type(16))) float f32x16;
typedef __attribute__((ext_vector_type(4))) unsigned int u32x4;

#define B_ 4
#define S_ 8192
#define D_ 1024
#define H_ 16
#define HD_ 64
#define W_ 512
#define M_ (B_*S_)

#define EXP2F(x) __builtin_amdgcn_exp2f(x)
#define MFMA16(a,b,c) __builtin_amdgcn_mfma_f32_16x16x32_bf16(a,b,c,0,0,0)
#define MFMA32(a,b,c) __builtin_amdgcn_mfma_f32_32x32x16_bf16(a,b,c,0,0,0)

__device__ __forceinline__ void async16(const void* g, void* l) {
  __builtin_amdgcn_global_load_lds(
      (const __attribute__((address_space(1))) unsigned int*)g,
      (__attribute__((address_space(3))) unsigned int*)l, 16, 0, 0);
}

// ---------------- cast f32 -> bf16 ----------------
__global__ void cast_f32_bf16(const float* __restrict__ in, bf16* __restrict__ out, int n4) {
  int i = blockIdx.x * blockDim.x + threadIdx.x;
  int stride = gridDim.x * blockDim.x;
  for (; i < n4; i += stride) {
    f32x4 v = ((const f32x4*)in)[i];
    bf16x4 o = { (bf16)v[0], (bf16)v[1], (bf16)v[2], (bf16)v[3] };
    ((bf16x4*)out)[i] = o;
  }
}

// ---------------- GEMM: C = A(MxK) * Bw(NxK)^T + bias ----------------
// Counted-vmcnt raw-barrier pipeline: prefetch loads stay in flight across barriers.
// MODE 0: bf16 out row-major   MODE 1: bf16 out V-transposed per batch   MODE 2: f32 out
template<int MODE>
__global__ void __launch_bounds__(256, 2) gemm_bt(
    const bf16* __restrict__ A, const bf16* __restrict__ Bw,
    const float* __restrict__ bias, void* __restrict__ outp, float scale)
{
  constexpr int K = D_, N = D_;
  __shared__ bf16 As[2][128*32];
  __shared__ bf16 Bs[2][128*32];
  int bid = blockIdx.x;
  int nid = (bid & 7) * 256 + (bid >> 3);     // bijective XCD swizzle (2048 % 8 == 0)
  int bm = nid >> 3, bn = nid & 7;
  const int tid = threadIdx.x, lane = tid & 63;
  const int w = tid >> 6, wr = w >> 1, wc = w & 1;
  f32x4 acc[4][4] = {};
  const int r0 = tid >> 2;
  const int kbyte = (tid & 3) * 16;
  const char* Ab = (const char*)(A + (size_t)bm * 128 * K);
  const char* Bb = (const char*)(Bw + (size_t)bn * 128 * K);

  // stage K-tile kt (elements) into buffer buf
  auto stage = [&](int kt, int buf) {
    const size_t cb = (size_t)kt * 2 + kbyte;
    async16(Ab + (size_t)r0      * (K*2) + cb, (char*)&As[buf][0] + tid*16);
    async16(Ab + (size_t)(r0+64) * (K*2) + cb, (char*)&As[buf][0] + 4096 + tid*16);
    async16(Bb + (size_t)r0      * (K*2) + cb, (char*)&Bs[buf][0] + tid*16);
    async16(Bb + (size_t)(r0+64) * (K*2) + cb, (char*)&Bs[buf][0] + 4096 + tid*16);
  };

  stage(0, 0);
  for (int i = 0; i < 32; ++i) {
    int cur = i & 1;
    if (i < 31) {
      stage((i + 1) * 32, cur ^ 1);
      asm volatile("s_waitcnt vmcnt(4)" ::: "memory");   // tile i landed; 4 in flight
    } else {
      asm volatile("s_waitcnt vmcnt(0)" ::: "memory");
    }
    asm volatile("s_barrier" ::: "memory");
    bf16x8 a[4], b[4];
#pragma unroll
    for (int mi = 0; mi < 4; ++mi)
      a[mi] = *(const bf16x8*)(&As[cur][0] + (wr*64 + mi*16 + (lane & 15))*32 + ((lane >> 4)*8));
#pragma unroll
    for (int ni = 0; ni < 4; ++ni)
      b[ni] = *(const bf16x8*)(&Bs[cur][0] + (wc*64 + ni*16 + (lane & 15))*32 + ((lane >> 4)*8));
#pragma unroll
    for (int mi = 0; mi < 4; ++mi)
#pragma unroll
      for (int ni = 0; ni < 4; ++ni)
        acc[mi][ni] = MFMA16(a[mi], b[ni], acc[mi][ni]);
    asm volatile("s_barrier" ::: "memory");   // all reads of buf cur done before restage
  }
  int row0 = bm*128 + wr*64, col0 = bn*128 + wc*64;
  int rsub = (lane >> 4) * 4;
#pragma unroll
  for (int ni = 0; ni < 4; ++ni) {
    int col = col0 + ni*16 + (lane & 15);
    float bz = bias[col];
#pragma unroll
    for (int mi = 0; mi < 4; ++mi) {
#pragma unroll
      for (int r = 0; r < 4; ++r) {
        int row = row0 + mi*16 + rsub + r;
        float v = (acc[mi][ni][r] + bz) * scale;
        if (MODE == 0) {
          ((bf16*)outp)[(size_t)row * N + col] = (bf16)v;
        } else if (MODE == 1) {
          ((bf16*)outp)[((size_t)(row >> 13) * D_ + col) * S_ + (row & (S_-1))] = (bf16)v;
        } else {
          ((float*)outp)[(size_t)row * N + col] = v;
        }
      }
    }
  }
}

// ---------------- attention v3 ----------------
// 4 waves x 32 q-rows, 32x32x16 MFMA, swapped QK^T, in-register P via
// cvt_pk_bf16 + permlane32_swap (no P-LDS), double-buffered swizzled K/V LDS.
// grid: 4096 blocks; 4 q-tile blocks of one (b,n,h) land on one XCD.
__global__ void __launch_bounds__(256, 3) attn_kernel(
    const bf16* __restrict__ Q, const bf16* __restrict__ Kb,
    const bf16* __restrict__ Vt, bf16* __restrict__ Ao)
{
  __shared__ char Klds[2][8192];   // [buf][64 keys x 128B (d-major, swizzled)]
  __shared__ char Vlds[2][8192];   // [buf][64 hd   x 128B (keys-major, swizzled)]
  int x = blockIdx.x;
  int qt = (x >> 3) & 3;
  int g  = (x & 7) + 8 * (x >> 5);          // group -> one XCD
  int h = g & 15, n = (g >> 4) & 15, b = g >> 8;
  int tid = threadIdx.x, lane = tid & 63, w = tid >> 6;
  int hi = lane >> 5, qv = lane & 31;       // this lane's q
  int qrow = n * W_ + qt * 128 + w * 32;

  const bf16* Qrow = Q + ((size_t)(b * S_ + qrow + qv)) * D_ + h * 64;
  bf16x8 Qf[4];
#pragma unroll
  for (int s = 0; s < 4; ++s) Qf[s] = *(const bf16x8*)(Qrow + s * 16 + hi * 8);

  const bf16* Kg = Kb + ((size_t)b * S_) * D_ + h * 64;
  const bf16* Vg = Vt + ((size_t)(b * H_ + h) * HD_) * S_;

  const int srow = tid >> 3, scol = tid & 7;
  const int sswz = (srow & 7) << 4;
  const int fswq = (qv & 7) << 4;           // fragment swizzle (row&7 == qv&7)

  f32x16 O0 = {}, O1 = {};
  float m_r = -3.0e38f, l_r = 0.f;

  const int c0 = (n == 0) ? 8 : 0;
  const int ksbase = (n - 1) * W_;

  u32x4 pk0, pk1, pv0, pv1;
  {  // prologue: stage chunk c0 into buffer 0
    int ks = ksbase + c0 * 64;
    pk0 = *(const u32x4*)(Kg + (size_t)(ks + srow)      * D_ + scol * 8);
    pk1 = *(const u32x4*)(Kg + (size_t)(ks + srow + 32) * D_ + scol * 8);
    pv0 = *(const u32x4*)(Vg + (size_t)srow        * S_ + ks + scol * 8);
    pv1 = *(const u32x4*)(Vg + (size_t)(srow + 32) * S_ + ks + scol * 8);
    *(u32x4*)(Klds[0] + srow        * 128 + ((scol * 16) ^ sswz)) = pk0;
    *(u32x4*)(Klds[0] + (srow + 32) * 128 + ((scol * 16) ^ sswz)) = pk1;
    *(u32x4*)(Vlds[0] + srow        * 128 + ((scol * 16) ^ sswz)) = pv0;
    *(u32x4*)(Vlds[0] + (srow + 32) * 128 + ((scol * 16) ^ sswz)) = pv1;
  }
  __syncthreads();
  int cur = 0;
  for (int c = c0; c < 16; ++c) {
    bool pre = (c < 15);
    if (pre) {
      int ks2 = ksbase + (c + 1) * 64;
      pk0 = *(const u32x4*)(Kg + (size_t)(ks2 + srow)      * D_ + scol * 8);
      pk1 = *(const u32x4*)(Kg + (size_t)(ks2 + srow + 32) * D_ + scol * 8);
      pv0 = *(const u32x4*)(Vg + (size_t)srow        * S_ + ks2 + scol * 8);
      pv1 = *(const u32x4*)(Vg + (size_t)(srow + 32) * S_ + ks2 + scol * 8);
    }
    const char* kbuf = Klds[cur];
    const char* vbuf = Vlds[cur];
    // ---- swapped QK^T: C[T][reg]: row=key=(reg&3)+8*(reg>>2)+4*hi (+32T), col=q=qv
    f32x16 C0 = {}, C1 = {};
    __builtin_amdgcn_s_setprio(1);
#pragma unroll
    for (int s = 0; s < 4; ++s) {
      bf16x8 k0 = *(const bf16x8*)(kbuf + qv * 128        + ((s * 32 + hi * 16) ^ fswq));
      bf16x8 k1 = *(const bf16x8*)(kbuf + (32 + qv) * 128 + ((s * 32 + hi * 16) ^ fswq));
      C0 = MFMA32(k0, Qf[s], C0);
      C1 = MFMA32(k1, Qf[s], C1);
    }
    __builtin_amdgcn_s_setprio(0);
    // ---- lane-local online softmax (exp2 domain; lane holds 32 scores of q=qv)
    float mx = C0[0];
#pragma unroll
    for (int r = 1; r < 16; ++r) mx = fmaxf(mx, C0[r]);
#pragma unroll
    for (int r = 0; r < 16; ++r) mx = fmaxf(mx, C1[r]);
    mx = fmaxf(mx, __shfl_xor(mx, 32));
    if (!__all(mx - m_r <= 8.0f)) {   // defer-max
      float mn = fmaxf(m_r, mx);
      float sc = EXP2F(m_r - mn);
      m_r = mn;
      l_r *= sc;
#pragma unroll
      for (int r = 0; r < 16; ++r) { O0[r] *= sc; O1[r] *= sc; }
    }
    float ls = 0.f;
    float p0[16], p1[16];
#pragma unroll
    for (int r = 0; r < 16; ++r) {
      p0[r] = EXP2F(C0[r] - m_r);
      p1[r] = EXP2F(C1[r] - m_r);
      ls += p0[r] + p1[r];
    }
    l_r += ls;
    // ---- pack P to bf16 dwords + cross-half exchange (in-register, no LDS)
    unsigned int L0[8], L1[8];
#pragma unroll
    for (int t = 0; t < 8; ++t) {
      asm("v_cvt_pk_bf16_f32 %0, %1, %2" : "=v"(L0[t]) : "v"(p0[2*t]), "v"(p0[2*t+1]));
      asm("v_cvt_pk_bf16_f32 %0, %1, %2" : "=v"(L1[t]) : "v"(p1[2*t]), "v"(p1[2*t+1]));
    }
    // after swap: L[0..3] = frag(s=0) dwords, L[4..7] = frag(s=1) dwords
    asm volatile("v_permlane32_swap_b32 %0, %1" : "+v"(L0[0]), "+v"(L0[2]));
    asm volatile("v_permlane32_swap_b32 %0, %1" : "+v"(L0[1]), "+v"(L0[3]));
    asm volatile("v_permlane32_swap_b32 %0, %1" : "+v"(L0[4]), "+v"(L0[6]));
    asm volatile("v_permlane32_swap_b32 %0, %1" : "+v"(L0[5]), "+v"(L0[7]));
    asm volatile("v_permlane32_swap_b32 %0, %1" : "+v"(L1[0]), "+v"(L1[2]));
    asm volatile("v_permlane32_swap_b32 %0, %1" : "+v"(L1[1]), "+v"(L1[3]));
    asm volatile("v_permlane32_swap_b32 %0, %1" : "+v"(L1[4]), "+v"(L1[6]));
    asm volatile("v_permlane32_swap_b32 %0, %1" : "+v"(L1[5]), "+v"(L1[7]));
    u32x4 F[2][2];
    F[0][0] = u32x4{L0[0], L0[1], L0[2], L0[3]};
    F[0][1] = u32x4{L0[4], L0[5], L0[6], L0[7]};
    F[1][0] = u32x4{L1[0], L1[1], L1[2], L1[3]};
    F[1][1] = u32x4{L1[4], L1[5], L1[6], L1[7]};
    // ---- PV: O[hd][q] += V^T x P^T   (A rows = hd, k = keys)
    __builtin_amdgcn_s_setprio(1);
#pragma unroll
    for (int T = 0; T < 2; ++T)
#pragma unroll
      for (int s = 0; s < 2; ++s) {
        bf16x8 pf = *(bf16x8*)&F[T][s];
        int kbyteoff = T * 64 + s * 32 + hi * 16;
        bf16x8 v0 = *(const bf16x8*)(vbuf + qv * 128        + (kbyteoff ^ fswq));
        bf16x8 v1 = *(const bf16x8*)(vbuf + (32 + qv) * 128 + (kbyteoff ^ fswq));
        O0 = MFMA32(v0, pf, O0);
        O1 = MFMA32(v1, pf, O1);
      }
    __builtin_amdgcn_s_setprio(0);
    // ---- write prefetched chunk into the other buffer, single barrier
    if (pre) {
      int nb = cur ^ 1;
      *(u32x4*)(Klds[nb] + srow        * 128 + ((scol * 16) ^ sswz)) = pk0;
      *(u32x4*)(Klds[nb] + (srow + 32) * 128 + ((scol * 16) ^ sswz)) = pk1;
      *(u32x4*)(Vlds[nb] + srow        * 128 + ((scol * 16) ^ sswz)) = pv0;
      *(u32x4*)(Vlds[nb] + (srow + 32) * 128 + ((scol * 16) ^ sswz)) = pv1;
    }
    __syncthreads();
    cur ^= 1;
  }
  // ---- final l reduce across halves, normalize, store
  float lt = l_r + __shfl_xor(l_r, 32);
  float inv = 1.0f / lt;
  size_t obase = ((size_t)(b * S_ + qrow + qv)) * D_ + h * 64;
#pragma unroll
  for (int ot = 0; ot < 2; ++ot) {
#pragma unroll
    for (int rq = 0; rq < 4; ++rq) {
      int hd = ot * 32 + 8 * rq + 4 * hi;
      bf16x4 ov;
#pragma unroll
      for (int j = 0; j < 4; ++j) {
        float val = (ot == 0 ? O0[rq*4 + j] : O1[rq*4 + j]) * inv;
        ov[j] = (bf16)val;
      }
      *(bf16x4*)(Ao + obase + hd) = ov;
    }
  }
}

extern "C" void kernel_launch(void* const* d_in, const int* in_sizes, int n_in,
                              void* d_out, int out_size, void* d_ws, size_t ws_size,
                              hipStream_t stream) {
  const float* x  = (const float*)d_in[0];
  const float* wq = (const float*)d_in[1];
  const float* bq = (const float*)d_in[2];
  const float* wk = (const float*)d_in[3];
  const float* bk = (const float*)d_in[4];
  const float* wv = (const float*)d_in[5];
  const float* bv = (const float*)d_in[6];
  const float* wo = (const float*)d_in[7];
  const float* bo = (const float*)d_in[8];
  float* out = (float*)d_out;

  char* ws = (char*)d_ws;
  const size_t sz = (size_t)M_ * D_ * 2;
  bf16* xb  = (bf16*)(ws + 0*sz);
  bf16* qb  = (bf16*)(ws + 1*sz);
  bf16* kb  = (bf16*)(ws + 2*sz);
  bf16* vt  = (bf16*)(ws + 3*sz);
  bf16* ao  = (bf16*)(ws + 4*sz);
  bf16* wqb = (bf16*)(ws + 5*sz);
  bf16* wkb = wqb + (size_t)D_*D_;
  bf16* wvb = wkb + (size_t)D_*D_;
  bf16* wob = wvb + (size_t)D_*D_;

  cast_f32_bf16<<<2048, 256, 0, stream>>>(x,  xb,  M_*D_/4);
  cast_f32_bf16<<<512,  256, 0, stream>>>(wq, wqb, D_*D_/4);
  cast_f32_bf16<<<512,  256, 0, stream>>>(wk, wkb, D_*D_/4);
  cast_f32_bf16<<<512,  256, 0, stream>>>(wv, wvb, D_*D_/4);
  cast_f32_bf16<<<512,  256, 0, stream>>>(wo, wob, D_*D_/4);

  // Q pre-scaled by (1/sqrt(64)) * log2(e) so attention exp runs in exp2 domain
  gemm_bt<0><<<2048, 256, 0, stream>>>(xb, wqb, bq, qb, 0.125f * 1.44269504f);
  gemm_bt<0><<<2048, 256, 0, stream>>>(xb, wkb, bk, kb, 1.0f);
  gemm_bt<1><<<2048, 256, 0, stream>>>(xb, wvb, bv, vt, 1.0f);    // V stored transposed

  attn_kernel<<<4096, 256, 0, stream>>>(qb, kb, vt, ao);

  gemm_bt<2><<<2048, 256, 0, stream>>>(ao, wob, bo, out, 1.0f);
}

// Round 6
// 563.179 us; speedup vs baseline: 2.2879x; 1.0218x over previous
//
#include <hip/hip_runtime.h>
#include <hip/hip_bf16.h>
#include <cstdint>

typedef __bf16 bf16;
typedef __attribute__((ext_vector_type(8))) __bf16 bf16x8;
typedef __attribute__((ext_vector_type(4))) __bf16 bf16x4;
typedef __attribute__((ext_vector_type(4))) float f32x4;
typedef __attribute__((ext_vector_type(16))) float f32x16;
typedef __attribute__((ext_vector_type(4))) unsigned int u32x4;

#define B_ 4
#define S_ 8192
#define D_ 1024
#define H_ 16
#define HD_ 64
#define W_ 512
#define M_ (B_*S_)

#define EXP2F(x) __builtin_amdgcn_exp2f(x)
#define MFMA16(a,b,c) __builtin_amdgcn_mfma_f32_16x16x32_bf16(a,b,c,0,0,0)
#define MFMA32(a,b,c) __builtin_amdgcn_mfma_f32_32x32x16_bf16(a,b,c,0,0,0)

__device__ __forceinline__ void async16(const void* g, void* l) {
  __builtin_amdgcn_global_load_lds(
      (const __attribute__((address_space(1))) unsigned int*)g,
      (__attribute__((address_space(3))) unsigned int*)l, 16, 0, 0);
}

// ---------------- fused cast f32 -> bf16 (x + 4 weights, one launch) --------
__device__ __forceinline__ void cast_region(const float* __restrict__ in,
                                            bf16* __restrict__ out, int n4,
                                            int i0, int stride) {
  for (int i = i0; i < n4; i += stride) {
    f32x4 v = ((const f32x4*)in)[i];
    bf16x4 o = { (bf16)v[0], (bf16)v[1], (bf16)v[2], (bf16)v[3] };
    ((bf16x4*)out)[i] = o;
  }
}

__global__ void cast_all(const float* __restrict__ x,  bf16* __restrict__ xb,
                         const float* __restrict__ wq, bf16* __restrict__ wqb,
                         const float* __restrict__ wk, bf16* __restrict__ wkb,
                         const float* __restrict__ wv, bf16* __restrict__ wvb,
                         const float* __restrict__ wo, bf16* __restrict__ wob) {
  int i0 = blockIdx.x * blockDim.x + threadIdx.x;
  int stride = gridDim.x * blockDim.x;
  cast_region(x,  xb,  M_*D_/4, i0, stride);
  cast_region(wq, wqb, D_*D_/4, i0, stride);
  cast_region(wk, wkb, D_*D_/4, i0, stride);
  cast_region(wv, wvb, D_*D_/4, i0, stride);
  cast_region(wo, wob, D_*D_/4, i0, stride);
}

// ---------------- GEMM: C = A(MxK) * Bw(NxK)^T + bias ----------------
// Counted-vmcnt raw-barrier pipeline (m97-structure, 128^2, BK=32).
// MODE 0: bf16 out row-major   MODE 1: bf16 out V-transposed per batch   MODE 2: f32 out
template<int MODE>
__global__ void __launch_bounds__(256, 2) gemm_bt(
    const bf16* __restrict__ A, const bf16* __restrict__ Bw,
    const float* __restrict__ bias, void* __restrict__ outp, float scale)
{
  constexpr int K = D_, N = D_;
  __shared__ bf16 As[2][128*32];
  __shared__ bf16 Bs[2][128*32];
  int bid = blockIdx.x;
  int nid = (bid & 7) * 256 + (bid >> 3);     // bijective XCD swizzle (2048 % 8 == 0)
  int bm = nid >> 3, bn = nid & 7;
  const int tid = threadIdx.x, lane = tid & 63;
  const int w = tid >> 6, wr = w >> 1, wc = w & 1;
  f32x4 acc[4][4] = {};
  const int r0 = tid >> 2;
  const int kbyte = (tid & 3) * 16;
  const char* Ab = (const char*)(A + (size_t)bm * 128 * K);
  const char* Bb = (const char*)(Bw + (size_t)bn * 128 * K);

  auto stage = [&](int kt, int buf) {
    const size_t cb = (size_t)kt * 2 + kbyte;
    async16(Ab + (size_t)r0      * (K*2) + cb, (char*)&As[buf][0] + tid*16);
    async16(Ab + (size_t)(r0+64) * (K*2) + cb, (char*)&As[buf][0] + 4096 + tid*16);
    async16(Bb + (size_t)r0      * (K*2) + cb, (char*)&Bs[buf][0] + tid*16);
    async16(Bb + (size_t)(r0+64) * (K*2) + cb, (char*)&Bs[buf][0] + 4096 + tid*16);
  };

  stage(0, 0);
  for (int i = 0; i < 32; ++i) {
    int cur = i & 1;
    if (i < 31) {
      stage((i + 1) * 32, cur ^ 1);
      asm volatile("s_waitcnt vmcnt(4)" ::: "memory");
    } else {
      asm volatile("s_waitcnt vmcnt(0)" ::: "memory");
    }
    asm volatile("s_barrier" ::: "memory");
    bf16x8 a[4], b[4];
#pragma unroll
    for (int mi = 0; mi < 4; ++mi)
      a[mi] = *(const bf16x8*)(&As[cur][0] + (wr*64 + mi*16 + (lane & 15))*32 + ((lane >> 4)*8));
#pragma unroll
    for (int ni = 0; ni < 4; ++ni)
      b[ni] = *(const bf16x8*)(&Bs[cur][0] + (wc*64 + ni*16 + (lane & 15))*32 + ((lane >> 4)*8));
#pragma unroll
    for (int mi = 0; mi < 4; ++mi)
#pragma unroll
      for (int ni = 0; ni < 4; ++ni)
        acc[mi][ni] = MFMA16(a[mi], b[ni], acc[mi][ni]);
    asm volatile("s_barrier" ::: "memory");
  }
  int row0 = bm*128 + wr*64, col0 = bn*128 + wc*64;
  int rsub = (lane >> 4) * 4;
#pragma unroll
  for (int ni = 0; ni < 4; ++ni) {
    int col = col0 + ni*16 + (lane & 15);
    float bz = bias[col];
#pragma unroll
    for (int mi = 0; mi < 4; ++mi) {
#pragma unroll
      for (int r = 0; r < 4; ++r) {
        int row = row0 + mi*16 + rsub + r;
        float v = (acc[mi][ni][r] + bz) * scale;
        if (MODE == 0) {
          ((bf16*)outp)[(size_t)row * N + col] = (bf16)v;
        } else if (MODE == 1) {
          ((bf16*)outp)[((size_t)(row >> 13) * D_ + col) * S_ + (row & (S_-1))] = (bf16)v;
        } else {
          ((float*)outp)[(size_t)row * N + col] = v;
        }
      }
    }
  }
}

// ---------------- attention v4 ----------------
// 4 waves x 32 q-rows, 32x32x16 MFMA, swapped QK^T, in-register P
// (cvt_pk + permlane32_swap). K/V staged via global_load_lds with
// pre-swizzled SOURCE (linear LDS dest, involution seg^(row&7)) into a
// ring of 3 buffers; counted vmcnt(4); ONE barrier per chunk.
__global__ void __launch_bounds__(256, 3) attn_kernel(
    const bf16* __restrict__ Q, const bf16* __restrict__ Kb,
    const bf16* __restrict__ Vt, bf16* __restrict__ Ao)
{
  __shared__ char Klds[3][8192];   // [slot][64 keys x 128B (d-major, swizzled)]
  __shared__ char Vlds[3][8192];   // [slot][64 hd   x 128B (keys-major, swizzled)]
  int x = blockIdx.x;
  int qt = (x >> 3) & 3;
  int g  = (x & 7) + 8 * (x >> 5);          // group -> one XCD
  int h = g & 15, n = (g >> 4) & 15, b = g >> 8;
  int tid = threadIdx.x, lane = tid & 63, w = tid >> 6;
  int hi = lane >> 5, qv = lane & 31;       // this lane's q
  int qrow = n * W_ + qt * 128 + w * 32;

  const bf16* Qrow = Q + ((size_t)(b * S_ + qrow + qv)) * D_ + h * 64;
  bf16x8 Qf[4];
#pragma unroll
  for (int s = 0; s < 4; ++s) Qf[s] = *(const bf16x8*)(Qrow + s * 16 + hi * 8);

  const bf16* Kg = Kb + ((size_t)b * S_) * D_ + h * 64;
  const bf16* Vg = Vt + ((size_t)(b * H_ + h) * HD_) * S_;

  // staging: thread -> (row = tid>>3, slot = tid&7); source seg pre-swizzled
  const int srow = tid >> 3;
  const int sseg = (tid & 7) ^ (srow & 7);
  const int fswq = (qv & 7) << 4;           // fragment swizzle on read

  f32x16 O0 = {}, O1 = {};
  float m_r = -3.0e38f, l_r = 0.f;

  const int c0 = (n == 0) ? 8 : 0;
  const int ksbase = (n - 1) * W_;

  auto stage = [&](int c) {
    int ks = ksbase + c * 64;
    int so = (c % 3) * 8192;
    const bf16* kr = Kg + (size_t)(ks + srow) * D_ + sseg * 8;
    async16(kr,            &Klds[0][0] + so + tid * 16);
    async16(kr + 32 * D_,  &Klds[0][0] + so + 4096 + tid * 16);
    const bf16* vr = Vg + (size_t)srow * S_ + ks + sseg * 8;
    async16(vr,            &Vlds[0][0] + so + tid * 16);
    async16(vr + (size_t)32 * S_, &Vlds[0][0] + so + 4096 + tid * 16);
  };

  // prologue: stage c0 and c0+1
  stage(c0);
  stage(c0 + 1);
  asm volatile("s_waitcnt vmcnt(4)" ::: "memory");
  asm volatile("s_barrier" ::: "memory");

  for (int c = c0; c < 16; ++c) {
    bool pre = (c + 2 < 16);
    if (pre) stage(c + 2);
    const char* kbuf = &Klds[0][0] + (c % 3) * 8192;
    const char* vbuf = &Vlds[0][0] + (c % 3) * 8192;
    // ---- swapped QK^T: C[T][reg]: row=key=(reg&3)+8*(reg>>2)+4*hi (+32T), col=q=qv
    f32x16 C0 = {}, C1 = {};
    __builtin_amdgcn_s_setprio(1);
#pragma unroll
    for (int s = 0; s < 4; ++s) {
      bf16x8 k0 = *(const bf16x8*)(kbuf + qv * 128        + ((s * 32 + hi * 16) ^ fswq));
      bf16x8 k1 = *(const bf16x8*)(kbuf + (32 + qv) * 128 + ((s * 32 + hi * 16) ^ fswq));
      C0 = MFMA32(k0, Qf[s], C0);
      C1 = MFMA32(k1, Qf[s], C1);
    }
    __builtin_amdgcn_s_setprio(0);
    // ---- lane-local online softmax (exp2 domain), max3-friendly reduce
    float mx = fmaxf(C0[0], C1[0]);
#pragma unroll
    for (int r = 1; r < 16; ++r) mx = fmaxf(fmaxf(mx, C0[r]), C1[r]);
    mx = fmaxf(mx, __shfl_xor(mx, 32));
    if (!__all(mx - m_r <= 8.0f)) {   // defer-max
      float mn = fmaxf(m_r, mx);
      float sc = EXP2F(m_r - mn);
      m_r = mn;
      l_r *= sc;
#pragma unroll
      for (int r = 0; r < 16; ++r) { O0[r] *= sc; O1[r] *= sc; }
    }
    float ls = 0.f;
    float p0[16], p1[16];
#pragma unroll
    for (int r = 0; r < 16; ++r) {
      p0[r] = EXP2F(C0[r] - m_r);
      p1[r] = EXP2F(C1[r] - m_r);
      ls += p0[r] + p1[r];
    }
    l_r += ls;
    // ---- pack P to bf16 dwords + cross-half exchange (in-register)
    unsigned int L0[8], L1[8];
#pragma unroll
    for (int t = 0; t < 8; ++t) {
      asm("v_cvt_pk_bf16_f32 %0, %1, %2" : "=v"(L0[t]) : "v"(p0[2*t]), "v"(p0[2*t+1]));
      asm("v_cvt_pk_bf16_f32 %0, %1, %2" : "=v"(L1[t]) : "v"(p1[2*t]), "v"(p1[2*t+1]));
    }
    asm volatile("v_permlane32_swap_b32 %0, %1" : "+v"(L0[0]), "+v"(L0[2]));
    asm volatile("v_permlane32_swap_b32 %0, %1" : "+v"(L0[1]), "+v"(L0[3]));
    asm volatile("v_permlane32_swap_b32 %0, %1" : "+v"(L0[4]), "+v"(L0[6]));
    asm volatile("v_permlane32_swap_b32 %0, %1" : "+v"(L0[5]), "+v"(L0[7]));
    asm volatile("v_permlane32_swap_b32 %0, %1" : "+v"(L1[0]), "+v"(L1[2]));
    asm volatile("v_permlane32_swap_b32 %0, %1" : "+v"(L1[1]), "+v"(L1[3]));
    asm volatile("v_permlane32_swap_b32 %0, %1" : "+v"(L1[4]), "+v"(L1[6]));
    asm volatile("v_permlane32_swap_b32 %0, %1" : "+v"(L1[5]), "+v"(L1[7]));
    u32x4 F[2][2];
    F[0][0] = u32x4{L0[0], L0[1], L0[2], L0[3]};
    F[0][1] = u32x4{L0[4], L0[5], L0[6], L0[7]};
    F[1][0] = u32x4{L1[0], L1[1], L1[2], L1[3]};
    F[1][1] = u32x4{L1[4], L1[5], L1[6], L1[7]};
    // ---- PV: O[hd][q] += V^T x P^T
    __builtin_amdgcn_s_setprio(1);
#pragma unroll
    for (int T = 0; T < 2; ++T)
#pragma unroll
      for (int s = 0; s < 2; ++s) {
        bf16x8 pf = *(bf16x8*)&F[T][s];
        int kbyteoff = T * 64 + s * 32 + hi * 16;
        bf16x8 v0 = *(const bf16x8*)(vbuf + qv * 128        + (kbyteoff ^ fswq));
        bf16x8 v1 = *(const bf16x8*)(vbuf + (32 + qv) * 128 + (kbyteoff ^ fswq));
        O0 = MFMA32(v0, pf, O0);
        O1 = MFMA32(v1, pf, O1);
      }
    __builtin_amdgcn_s_setprio(0);
    // ---- counted drain: keep c+2's 4 loads in flight; single barrier
    if (pre) {
      asm volatile("s_waitcnt vmcnt(4)" ::: "memory");
    } else {
      asm volatile("s_waitcnt vmcnt(0)" ::: "memory");
    }
    asm volatile("s_barrier" ::: "memory");
  }
  // ---- final l reduce across halves, normalize, store
  float lt = l_r + __shfl_xor(l_r, 32);
  float inv = 1.0f / lt;
  size_t obase = ((size_t)(b * S_ + qrow + qv)) * D_ + h * 64;
#pragma unroll
  for (int ot = 0; ot < 2; ++ot) {
#pragma unroll
    for (int rq = 0; rq < 4; ++rq) {
      int hd = ot * 32 + 8 * rq + 4 * hi;
      bf16x4 ov;
#pragma unroll
      for (int j = 0; j < 4; ++j) {
        float val = (ot == 0 ? O0[rq*4 + j] : O1[rq*4 + j]) * inv;
        ov[j] = (bf16)val;
      }
      *(bf16x4*)(Ao + obase + hd) = ov;
    }
  }
}

extern "C" void kernel_launch(void* const* d_in, const int* in_sizes, int n_in,
                              void* d_out, int out_size, void* d_ws, size_t ws_size,
                              hipStream_t stream) {
  const float* x  = (const float*)d_in[0];
  const float* wq = (const float*)d_in[1];
  const float* bq = (const float*)d_in[2];
  const float* wk = (const float*)d_in[3];
  const float* bk = (const float*)d_in[4];
  const float* wv = (const float*)d_in[5];
  const float* bv = (const float*)d_in[6];
  const float* wo = (const float*)d_in[7];
  const float* bo = (const float*)d_in[8];
  float* out = (float*)d_out;

  char* ws = (char*)d_ws;
  const size_t sz = (size_t)M_ * D_ * 2;
  bf16* xb  = (bf16*)(ws + 0*sz);
  bf16* qb  = (bf16*)(ws + 1*sz);
  bf16* kb  = (bf16*)(ws + 2*sz);
  bf16* vt  = (bf16*)(ws + 3*sz);
  bf16* ao  = (bf16*)(ws + 4*sz);
  bf16* wqb = (bf16*)(ws + 5*sz);
  bf16* wkb = wqb + (size_t)D_*D_;
  bf16* wvb = wkb + (size_t)D_*D_;
  bf16* wob = wvb + (size_t)D_*D_;

  cast_all<<<2048, 256, 0, stream>>>(x, xb, wq, wqb, wk, wkb, wv, wvb, wo, wob);

  // Q pre-scaled by (1/sqrt(64)) * log2(e) so attention exp runs in exp2 domain
  gemm_bt<0><<<2048, 256, 0, stream>>>(xb, wqb, bq, qb, 0.125f * 1.44269504f);
  gemm_bt<0><<<2048, 256, 0, stream>>>(xb, wkb, bk, kb, 1.0f);
  gemm_bt<1><<<2048, 256, 0, stream>>>(xb, wvb, bv, vt, 1.0f);    // V stored transposed

  attn_kernel<<<4096, 256, 0, stream>>>(qb, kb, vt, ao);

  gemm_bt<2><<<2048, 256, 0, stream>>>(ao, wob, bo, out, 1.0f);
}